// Round 10
// baseline (300.026 us; speedup 1.0000x reference)
//
#include <hip/hip_runtime.h>
#include <math.h>

#define NN 1024
#define HID 64
#define HEADD 128
#define NODE_DIM 14
#define BATCH 32
#define CAP 64
#define ROWS (BATCH * NN)   // 32768
#define RPW 8               // rows per wave in layer kernels

// ---- swizzles (XCD-aware: blk%8 pins a batch's slab to one XCD L2) --------
__device__ __forceinline__ int swz4(int blk, int wv) {
    int x = blk & 7, q = blk >> 3;
    int batch = x + 8 * (q >> 8);
    return batch * NN + ((q & 255) << 2) + wv;
}
__device__ __forceinline__ int swz32(int blk, int wv) {
    int x = blk & 7, q = blk >> 3;          // q in [0,128)
    int batch = x + 8 * (q >> 5);
    return batch * NN + ((q & 31) << 5) + wv * RPW;
}

__device__ __forceinline__ float rl_f(float v, int k) {
    return __int_as_float(__builtin_amdgcn_readlane(__float_as_int(v), k));
}

// ---------------- K1: CSR build (ballot) + g1 = x @ W1 + zero pooled --------
__global__ __launch_bounds__(256) void k_build(const float* __restrict__ adj,
                                               const float* __restrict__ x,
                                               const float* __restrict__ W1,
                                               unsigned short* __restrict__ csr,
                                               int* __restrict__ nnz_g,
                                               float* __restrict__ dinv,
                                               float* __restrict__ g1,
                                               float* __restrict__ pooled) {
    __shared__ float sW1[NODE_DIM * HID];
    for (int i = threadIdx.x; i < NODE_DIM * HID; i += 256) sW1[i] = W1[i];
    if (blockIdx.x < 8) pooled[blockIdx.x * 256 + threadIdx.x] = 0.f;
    int wv = threadIdx.x >> 6, lane = threadIdx.x & 63;
    int row = swz4(blockIdx.x, wv);
    const float4* rp = reinterpret_cast<const float4*>(adj + (size_t)row * NN);
    unsigned long long lt = ((unsigned long long)1 << lane) - 1;
    int base = 0;
#pragma unroll
    for (int j = 0; j < 4; ++j) {
        float4 v = rp[lane + 64 * j];
        float vv[4] = {v.x, v.y, v.z, v.w};
#pragma unroll
        for (int k = 0; k < 4; ++k) {
            unsigned long long mk = __ballot(vv[k] != 0.0f);
            if (mk) {                         // wave-uniform: skip empty masks (~53%)
                if (vv[k] != 0.0f) {
                    int pos = base + __popcll(mk & lt);
                    if (pos < CAP)
                        csr[row * CAP + pos] = (unsigned short)((lane + 64 * j) * 4 + k);
                }
                base += __popcll(mk);
            }
        }
    }
    if (lane == 0) {
        nnz_g[row] = base < CAP ? base : CAP;
        dinv[row] = 1.0f / sqrtf((float)(base < 1 ? 1 : base));
    }
    __syncthreads();
    float acc = 0.f;
    const float* xr = x + (size_t)row * NODE_DIM;
#pragma unroll
    for (int d = 0; d < NODE_DIM; ++d) acc += xr[d] * sW1[d * HID + lane];
    g1[(size_t)row * HID + lane] = acc;
}

// 8-row interleaved SpMM: per k-step, 8 independent gathers in flight.
// dv lanes >= n[r] are zero, so k >= n[r] contributes exactly +0.0 (branch-free).
__device__ __forceinline__ void spmm8(const float* __restrict__ g_in,
                                      int bbase, const int n[RPW],
                                      const int idx[RPW], const float dv[RPW],
                                      int lane, float acc[RPW]) {
    int nmax = 0;
#pragma unroll
    for (int r = 0; r < RPW; ++r) { acc[r] = 0.f; nmax = n[r] > nmax ? n[r] : nmax; }
    for (int k = 0; k < nmax; ++k) {
        float w[RPW], v[RPW];
#pragma unroll
        for (int r = 0; r < RPW; ++r) {
            int j = __builtin_amdgcn_readlane(idx[r], k);
            w[r] = rl_f(dv[r], k);
            v[r] = g_in[(bbase + j) * HID + lane];
        }
#pragma unroll
        for (int r = 0; r < RPW; ++r) acc[r] += w[r] * v[r];
    }
}

// ---------------- K2/K3: g_out = relu(D A D g_in + bias) @ W ----------------
// W staged in LDS (64 VGPRs freed vs register-resident -> no spill at the
// 128-VGPR/4-wave cap). Epilogue broadcast via readlane (VALU), NOT shfl
// (ds_bpermute) -- LDS pipe sees only the 64 amortized ds_read_b32 per wave.
__global__ __launch_bounds__(256, 4) void k_layer(const float* __restrict__ g_in,
                                                  const unsigned short* __restrict__ csr,
                                                  const int* __restrict__ nnz_g,
                                                  const float* __restrict__ dinv,
                                                  const float* __restrict__ bias,
                                                  const float* __restrict__ W,
                                                  float* __restrict__ g_out) {
    __shared__ float sW[HID * HID];            // 16 KB
    for (int i = threadIdx.x; i < HID * HID; i += 256) sW[i] = W[i];
    int wv = threadIdx.x >> 6, lane = threadIdx.x & 63;
    int row0 = swz32(blockIdx.x, wv);
    int bbase = row0 & ~(NN - 1);
    float bb = bias[lane];
    int n[RPW], idx[RPW];
    float dv[RPW];
#pragma unroll
    for (int r = 0; r < RPW; ++r) {
        int row = row0 + r;
        n[r] = __builtin_amdgcn_readfirstlane(nnz_g[row]);
        idx[r] = (lane < n[r]) ? (int)csr[row * CAP + lane] : 0;
        dv[r] = (lane < n[r]) ? dinv[bbase + idx[r]] : 0.f;
    }
    float acc[RPW];
    spmm8(g_in, bbase, n, idx, dv, lane, acc);
    float h[RPW];
#pragma unroll
    for (int r = 0; r < RPW; ++r)
        h[r] = fmaxf(dinv[row0 + r] * acc[r] + bb, 0.f);
    __syncthreads();                           // sW ready
    float o[RPW];
#pragma unroll
    for (int r = 0; r < RPW; ++r) o[r] = 0.f;
    for (int d = 0; d < HID; ++d) {
        float w = sW[d * HID + lane];          // 1 ds_read / 8 rows, conflict-free
#pragma unroll
        for (int r = 0; r < RPW; ++r) o[r] += rl_f(h[r], d) * w;
    }
#pragma unroll
    for (int r = 0; r < RPW; ++r)
        g_out[(size_t)(row0 + r) * HID + lane] = o[r];
}

// ---------------- K4: h3 = relu(DAD g3 + b3); pool --------------------------
__global__ __launch_bounds__(256, 4) void k_layer3(const float* __restrict__ g_in,
                                                   const unsigned short* __restrict__ csr,
                                                   const int* __restrict__ nnz_g,
                                                   const float* __restrict__ dinv,
                                                   const float* __restrict__ bias,
                                                   float* __restrict__ pooled) {
    __shared__ float sred[4][HID];
    int wv = threadIdx.x >> 6, lane = threadIdx.x & 63;
    int row0 = swz32(blockIdx.x, wv);
    int bbase = row0 & ~(NN - 1);
    float bb = bias[lane];
    int n[RPW], idx[RPW];
    float dv[RPW];
#pragma unroll
    for (int r = 0; r < RPW; ++r) {
        int row = row0 + r;
        n[r] = __builtin_amdgcn_readfirstlane(nnz_g[row]);
        idx[r] = (lane < n[r]) ? (int)csr[row * CAP + lane] : 0;
        dv[r] = (lane < n[r]) ? dinv[bbase + idx[r]] : 0.f;
    }
    float acc[RPW];
    spmm8(g_in, bbase, n, idx, dv, lane, acc);
    float s = 0.f;
#pragma unroll
    for (int r = 0; r < RPW; ++r)
        s += fmaxf(dinv[row0 + r] * acc[r] + bb, 0.f);
    sred[wv][lane] = s;
    __syncthreads();
    if (wv == 0) {
        float tot = sred[0][lane] + sred[1][lane] + sred[2][lane] + sred[3][lane];
        atomicAdd(&pooled[(bbase >> 10) * HID + lane], tot);
    }
}

// ---------------- K5: head ---------------------------------------------------
__global__ __launch_bounds__(128) void k_head(const float* __restrict__ pooled_sum,
                                              const float* __restrict__ Wf1,
                                              const float* __restrict__ bf1,
                                              const float* __restrict__ Wf2,
                                              const float* __restrict__ bf2,
                                              float* __restrict__ out) {
    int b = blockIdx.x, t = threadIdx.x;
    __shared__ float p[HID];
    __shared__ float hid[HEADD];
    if (t < HID) p[t] = pooled_sum[b * HID + t] * (1.0f / NN);
    __syncthreads();
    float acc = bf1[t];
    for (int d = 0; d < HID; ++d) acc += p[d] * Wf1[d * HEADD + t];
    hid[t] = fmaxf(acc, 0.f);
    __syncthreads();
    if (t < 64) {
        float v = hid[t] * Wf2[t] + hid[t + 64] * Wf2[t + 64];
#pragma unroll
        for (int off = 32; off > 0; off >>= 1) v += __shfl_down(v, off, 64);
        if (t == 0) out[b] = v + bf2[0];
    }
}

extern "C" void kernel_launch(void* const* d_in, const int* in_sizes, int n_in,
                              void* d_out, int out_size, void* d_ws, size_t ws_size,
                              hipStream_t stream) {
    const float* x   = (const float*)d_in[0];
    const float* adj = (const float*)d_in[1];
    const float* W1  = (const float*)d_in[2];
    const float* b1  = (const float*)d_in[3];
    const float* W2  = (const float*)d_in[4];
    const float* b2  = (const float*)d_in[5];
    const float* W3  = (const float*)d_in[6];
    const float* b3  = (const float*)d_in[7];
    const float* Wf1 = (const float*)d_in[8];
    const float* bf1 = (const float*)d_in[9];
    const float* Wf2 = (const float*)d_in[10];
    const float* bf2 = (const float*)d_in[11];
    float* out = (float*)d_out;

    // ws carve: csr(ushort) 4MB | nnz 128KB | dinv 128KB | pooled 16KB | g1,g2,g3 8MB
    char* ws = (char*)d_ws;
    size_t off = 0;
    unsigned short* csr = (unsigned short*)(ws + off); off += (size_t)ROWS * CAP * 2;
    int*   nnz_g  = (int*)(ws + off);   off += (size_t)ROWS * 4;
    float* dinv   = (float*)(ws + off); off += (size_t)ROWS * 4;
    float* pooled = (float*)(ws + off); off += 4096 * 4;
    float* g1     = (float*)(ws + off); off += (size_t)ROWS * HID * 4;
    float* g2     = (float*)(ws + off); off += (size_t)ROWS * HID * 4;
    float* g3     = (float*)(ws + off);

    k_build <<<ROWS / 4, 256, 0, stream>>>(adj, x, W1, csr, nnz_g, dinv, g1, pooled);
    k_layer <<<ROWS / 32, 256, 0, stream>>>(g1, csr, nnz_g, dinv, b1, W2, g2);
    k_layer <<<ROWS / 32, 256, 0, stream>>>(g2, csr, nnz_g, dinv, b2, W3, g3);
    k_layer3<<<ROWS / 32, 256, 0, stream>>>(g3, csr, nnz_g, dinv, b3, pooled);
    k_head  <<<BATCH, 128, 0, stream>>>(pooled, Wf1, bf1, Wf2, bf2, out);
}